// Round 9
// baseline (5504.840 us; speedup 1.0000x reference)
//
#include <hip/hip_runtime.h>
#include <hip/hip_bf16.h>

#define N_USER 60000
#define N_ITEM 120000
#define NTOT   180000
#define NNZ_ADJ 3600000
#define NNZ_UG   960000
#define NNZ_IG  1920000

#define RSB     2048        // rows per super-bin
#define NSB_ADJ ((NTOT  + RSB - 1) / RSB)   // 88
#define NSB_UG  ((N_USER+ RSB - 1) / RSB)   // 30
#define NSB_IG  ((N_ITEM+ RSB - 1) / RSB)   // 59
#define CAPA_SB 43008       // mean 40960 + 10 sigma
#define CAPU_SB 34816       // mean 32768 + 11 sigma
#define CAPI_SB 34816       // mean 32768 + 11 sigma
#define CHUNK   4096

typedef __hip_bfloat16 bf16;

// load float element i from input tensor of unknown dtype: flag=1 -> fp32, 0 -> bf16
__device__ __forceinline__ float ldf(const void* p, long i, int f) {
    return f ? ((const float*)p)[i] : __bfloat162float(((const bf16*)p)[i]);
}

// pack two fp32 -> one uint holding 2 bf16 (RNE via __float2bfloat16)
__device__ __forceinline__ unsigned pk2(float a, float b) {
    unsigned short lo = __bfloat16_as_ushort(__float2bfloat16(a));
    unsigned short hi = __bfloat16_as_ushort(__float2bfloat16(b));
    return (unsigned)lo | ((unsigned)hi << 16);
}

// ---------------- dtype detector (adj_vals >= 0 -> bf16 words have bit15==0) ----
__global__ void k_detect(const void* __restrict__ vals, int* __restrict__ flag) {
    if (threadIdx.x == 0 && blockIdx.x == 0) {
        const unsigned short* w = (const unsigned short*)vals;
        int cnt = 0;
        for (int i = 0; i < 512; i += 2) cnt += (w[i] >> 15) & 1;
        *flag = (cnt > 16) ? 1 : 0;
    }
}

// ---------------- cast user/item emb -> ego bf16 ----------------
__global__ __launch_bounds__(256) void k_cast16(const void* __restrict__ ue,
                                                const void* __restrict__ ie,
                                                bf16* __restrict__ ego16,
                                                const int* __restrict__ flag) {
    int f = *flag;
    long i = (long)blockIdx.x * 256 + threadIdx.x;   // NTOT*64 = 11,520,000
    const long uN = (long)N_USER * 64;
    if (i < (long)NTOT * 64) {
        float v = (i < uN) ? ldf(ue, i, f) : ldf(ie, i - uN, f);
        ego16[i] = __float2bfloat16(v);
    }
}

// ================= two-level binned build =================
__global__ __launch_bounds__(256) void k_initpos(int* __restrict__ sbpos, int nsb, int cap) {
    int i = blockIdx.x * 256 + threadIdx.x;
    if (i < nsb) sbpos[i * 16] = i * cap;
}

// L1: partition edges into <=88 super-bins (2048 rows each).
// Record: {rl(11b)<<18 | col(18b), val_f32}
__global__ __launch_bounds__(256) void k_part(const int* __restrict__ rows,
                                              const int* __restrict__ cols,
                                              const void* __restrict__ vals,
                                              uint2* __restrict__ rec,
                                              int* __restrict__ sbpos,
                                              int nnz,
                                              const int* __restrict__ flag) {
    __shared__ int lcnt[96];
    __shared__ int lbase[96];
    int f = *flag;
    int t = threadIdx.x;
    int base = blockIdx.x * CHUNK;
    if (t < 96) lcnt[t] = 0;
    __syncthreads();
    for (int k = 0; k < CHUNK / 256; k++) {
        int e = base + k * 256 + t;
        if (e < nnz) atomicAdd(&lcnt[rows[e] >> 11], 1);
    }
    __syncthreads();
    if (t < 96) {
        int c = lcnt[t];
        lbase[t] = c ? atomicAdd(&sbpos[t * 16], c) : 0;
        lcnt[t] = 0;
    }
    __syncthreads();
    for (int k = 0; k < CHUNK / 256; k++) {
        int e = base + k * 256 + t;
        if (e < nnz) {
            int r = rows[e];
            int sb = r >> 11;
            int o = atomicAdd(&lcnt[sb], 1);
            unsigned meta = ((unsigned)(r & 2047) << 18) | (unsigned)cols[e];
            rec[lbase[sb] + o] = make_uint2(meta, __float_as_uint(ldf(vals, e, f)));
        }
    }
}

// L2: per-super-bin counting sort into row order; emits absolute [rstart, rend).
__global__ __launch_bounds__(1024) void k_sortsb(const uint2* __restrict__ rec,
                                                 uint2* __restrict__ rec2,
                                                 int* __restrict__ rstart,
                                                 int* __restrict__ rend,
                                                 const int* __restrict__ sbpos,
                                                 int cap, int n_rows) {
    __shared__ int cnt[RSB];
    __shared__ int pos[RSB];
    __shared__ int carry;
    int b = blockIdx.x, t = threadIdx.x;
    int s = b * cap;
    int e = sbpos[b * 16];           // final fill cursor
    cnt[t] = 0; cnt[t + 1024] = 0;
    if (t == 0) carry = 0;
    __syncthreads();
    for (int j = s + t; j < e; j += 1024)
        atomicAdd(&cnt[rec[j].x >> 18], 1);
    __syncthreads();
    for (int tile = 0; tile < 2; tile++) {
        int i = tile * 1024 + t;
        int v = cnt[i];
        pos[i] = v;
        __syncthreads();
        for (int d = 1; d < 1024; d <<= 1) {
            int w = (t >= d) ? pos[i - d] : 0;
            __syncthreads();
            if (t >= d) pos[i] += w;
            __syncthreads();
        }
        int inc = pos[i];            // inclusive within tile
        int ex  = carry + inc - v;   // exclusive global
        __syncthreads();
        pos[i] = ex;
        if (t == 1023) carry += inc;
        __syncthreads();
    }
    int row0 = b * RSB;
    for (int i = t; i < RSB; i += 1024) {
        int row = row0 + i;
        if (row < n_rows) {
            rstart[row] = s + pos[i];
            rend[row]   = s + pos[i] + cnt[i];
        }
    }
    __syncthreads();
    for (int j = s + t; j < e; j += 1024) {
        uint2 r = rec[j];
        int o = atomicAdd(&pos[r.x >> 18], 1);
        rec2[s + o] = r;
    }
}

// ================= CSR SpMM, bf16 x: one row per 8-lane octet =================
__global__ __launch_bounds__(256) void k_spmm_bf(const int* __restrict__ rstart,
                                                 const int* __restrict__ rend,
                                                 const uint2* __restrict__ rec,
                                                 const bf16* __restrict__ x,
                                                 float* __restrict__ out,
                                                 int n_rows) {
    int row = blockIdx.x * 32 + (threadIdx.x >> 3);
    int p = threadIdx.x & 7;
    if (row >= n_rows) return;
    int s = rstart[row], e = rend[row];
    const uint4* xb = (const uint4*)x;   // 8 bf16 per uint4
    float a[8];
#pragma unroll
    for (int i = 0; i < 8; i++) a[i] = 0.0f;
    for (int j = s; j < e; j++) {
        uint2 r = rec[j];
        int col = r.x & 0x3FFFF;
        float v = __uint_as_float(r.y);
        uint4 q = xb[(long)col * 8 + p];
        a[0] += v * __uint_as_float(q.x << 16);
        a[1] += v * __uint_as_float(q.x & 0xFFFF0000u);
        a[2] += v * __uint_as_float(q.y << 16);
        a[3] += v * __uint_as_float(q.y & 0xFFFF0000u);
        a[4] += v * __uint_as_float(q.z << 16);
        a[5] += v * __uint_as_float(q.z & 0xFFFF0000u);
        a[6] += v * __uint_as_float(q.w << 16);
        a[7] += v * __uint_as_float(q.w & 0xFFFF0000u);
    }
    float* o = out + (long)row * 64 + p * 8;
    *(float4*)(o + 0) = make_float4(a[0], a[1], a[2], a[3]);
    *(float4*)(o + 4) = make_float4(a[4], a[5], a[6], a[7]);
}

// ---------------- Y[M,64] = act(X[M,64] @ W[64,64] + b) -> bf16 ----------------
// ACT: 1 = elu, 2 = relu
// __launch_bounds__(256,4): cap 128 VGPR -- acc[64] must stay in registers
// (round-8 PMC: default allocator chose 64 VGPR and spilled acc -> 4.5x FETCH)
template <int ACT>
__global__ __launch_bounds__(256, 4) void k_gemm64(const float* __restrict__ X,
                                                   const void* __restrict__ W,
                                                   const void* __restrict__ b,
                                                   bf16* __restrict__ Y, int M,
                                                   const int* __restrict__ flag) {
    __shared__ float Wl[64][64];
    __shared__ float bl[64];
    int f = *flag;
    int tid = threadIdx.x;
    for (int i = tid; i < 4096; i += 256) Wl[i >> 6][i & 63] = ldf(W, i, f);
    if (tid < 64) bl[tid] = ldf(b, tid, f);
    __syncthreads();

    int r = blockIdx.x * 256 + tid;
    if (r >= M) return;
    const float* xr = X + (long)r * 64;

    float acc[64];
#pragma unroll
    for (int j = 0; j < 64; j++) acc[j] = bl[j];

    for (int k4 = 0; k4 < 64; k4 += 4) {
        float4 xv = *(const float4*)(xr + k4);
#pragma unroll
        for (int kk = 0; kk < 4; kk++) {
            float xs = (kk == 0) ? xv.x : (kk == 1) ? xv.y : (kk == 2) ? xv.z : xv.w;
#pragma unroll
            for (int j = 0; j < 64; j += 4) {
                float4 w4 = *(const float4*)&Wl[k4 + kk][j];
                acc[j + 0] += xs * w4.x;
                acc[j + 1] += xs * w4.y;
                acc[j + 2] += xs * w4.z;
                acc[j + 3] += xs * w4.w;
            }
        }
    }

    uint4* y = (uint4*)(Y + (long)r * 64);
#pragma unroll
    for (int q = 0; q < 8; q++) {
        float v[8];
#pragma unroll
        for (int i = 0; i < 8; i++) {
            float t2 = acc[q * 8 + i];
            if (ACT == 2) t2 = fmaxf(t2, 0.0f);
            else          t2 = (t2 > 0.0f) ? t2 : (expf(t2) - 1.0f);
            v[i] = t2;
        }
        y[q] = make_uint4(pk2(v[0], v[1]), pk2(v[2], v[3]),
                          pk2(v[4], v[5]), pk2(v[6], v[7]));
    }
}

// ---------------- fused NGCF layer + l2norm; ego bf16 updated IN PLACE --------
// __launch_bounds__(256,4): see k_gemm64 note (spill fix)
__global__ __launch_bounds__(256, 4) void k_layer(const float* __restrict__ S,
                                                  bf16* __restrict__ E16,
                                                  const void* __restrict__ Wgc,
                                                  const void* __restrict__ bgc,
                                                  const void* __restrict__ Wbi,
                                                  const void* __restrict__ bbi,
                                                  long woff, long boff,
                                                  bf16* __restrict__ nm, int M,
                                                  const int* __restrict__ flag) {
    __shared__ float W1[64][64];
    __shared__ float W2[64][64];
    __shared__ float bl[64];
    int f = *flag;
    int tid = threadIdx.x;
    for (int i = tid; i < 4096; i += 256) {
        W1[i >> 6][i & 63] = ldf(Wgc, woff + i, f);
        W2[i >> 6][i & 63] = ldf(Wbi, woff + i, f);
    }
    if (tid < 64) bl[tid] = ldf(bgc, boff + tid, f) + ldf(bbi, boff + tid, f);
    __syncthreads();

    int r = blockIdx.x * 256 + tid;
    if (r >= M) return;
    const float* sr = S + (long)r * 64;
    const uint2* ep = (const uint2*)(E16 + (long)r * 64);   // 4 bf16 per uint2

    float acc[64];
#pragma unroll
    for (int j = 0; j < 64; j++) acc[j] = bl[j];

    for (int k4 = 0; k4 < 64; k4 += 4) {
        float4 sv = *(const float4*)(sr + k4);
        uint2 eq = ep[k4 >> 2];
        float e0 = __uint_as_float(eq.x << 16);
        float e1 = __uint_as_float(eq.x & 0xFFFF0000u);
        float e2 = __uint_as_float(eq.y << 16);
        float e3 = __uint_as_float(eq.y & 0xFFFF0000u);
#pragma unroll
        for (int kk = 0; kk < 4; kk++) {
            float xs = (kk == 0) ? sv.x : (kk == 1) ? sv.y : (kk == 2) ? sv.z : sv.w;
            float xe = ((kk == 0) ? e0 : (kk == 1) ? e1 : (kk == 2) ? e2 : e3) * xs;
#pragma unroll
            for (int j = 0; j < 64; j += 4) {
                float4 w1 = *(const float4*)&W1[k4 + kk][j];
                float4 w2 = *(const float4*)&W2[k4 + kk][j];
                acc[j + 0] += xs * w1.x + xe * w2.x;
                acc[j + 1] += xs * w1.y + xe * w2.y;
                acc[j + 2] += xs * w1.z + xe * w2.z;
                acc[j + 3] += xs * w1.w + xe * w2.w;
            }
        }
    }

    float ss = 0.0f;
#pragma unroll
    for (int j = 0; j < 64; j++) {
        float v = acc[j];
        v = (v > 0.0f) ? v : 0.2f * v;
        acc[j] = v;
        ss += v * v;
    }
    float sc = 1.0f / fmaxf(sqrtf(ss), 1e-12f);

    uint4* er = (uint4*)(E16 + (long)r * 64);
    uint4* nr = (uint4*)(nm + (long)r * 64);
#pragma unroll
    for (int q = 0; q < 8; q++) {
        float* a = acc + q * 8;
        er[q] = make_uint4(pk2(a[0], a[1]), pk2(a[2], a[3]),
                           pk2(a[4], a[5]), pk2(a[6], a[7]));
        nr[q] = make_uint4(pk2(a[0] * sc, a[1] * sc), pk2(a[2] * sc, a[3] * sc),
                           pk2(a[4] * sc, a[5] * sc), pk2(a[6] * sc, a[7] * sc));
    }
}

// ---------------- final gather into output ----------------
__global__ __launch_bounds__(64) void k_gather(const int* __restrict__ users,
                                               const int* __restrict__ pos,
                                               const int* __restrict__ neg,
                                               const void* __restrict__ ue,
                                               const void* __restrict__ ie,
                                               const bf16* __restrict__ n1,
                                               const bf16* __restrict__ n2,
                                               const bf16* __restrict__ n3,
                                               const bf16* __restrict__ uh,
                                               const bf16* __restrict__ ih,
                                               void* __restrict__ out,
                                               const int* __restrict__ flag) {
    int f = *flag;
    int b = blockIdx.x;           // 0..12287: [users | pos | neg] x 4096
    int which = b >> 12;
    int s = b & 4095;
    int lane = threadIdx.x;       // 64
    long ebase, nbase;
    const void* e0;
    const bf16* hh;
    if (which == 0) {
        int r = users[s];
        e0 = ue; ebase = (long)r * 64;
        hh = uh + (long)r * 64;
        nbase = (long)r * 64;
    } else {
        int r = (which == 1) ? pos[s] : neg[s];
        e0 = ie; ebase = (long)r * 64;
        hh = ih + (long)r * 64;
        nbase = (long)(N_USER + r) * 64;
    }
    float o0 = ldf(e0, ebase + lane, f);
    float o1 = __bfloat162float(n1[nbase + lane]);
    float o2 = __bfloat162float(n2[nbase + lane]);
    float o3 = __bfloat162float(n3[nbase + lane]);
    float o4 = __bfloat162float(hh[lane]);
    long ob = (long)b * 320;
    if (f) {
        float* o = (float*)out + ob;
        o[lane] = o0; o[64 + lane] = o1; o[128 + lane] = o2;
        o[192 + lane] = o3; o[256 + lane] = o4;
    } else {
        bf16* o = (bf16*)out + ob;
        o[lane]       = __float2bfloat16(o0);
        o[64 + lane]  = __float2bfloat16(o1);
        o[128 + lane] = __float2bfloat16(o2);
        o[192 + lane] = __float2bfloat16(o3);
        o[256 + lane] = __float2bfloat16(o4);
    }
}

// host-side helper: two-level build of row-sorted packed records for one graph
static void build_graph(const int* rows, const int* cols, const void* vals,
                        int nnz, int nsb, int cap, int n_rows,
                        int* sbpos, uint2* recTmp, uint2* rec2,
                        int* rstart, int* rend,
                        const int* FLAG, hipStream_t stream) {
    k_initpos<<<1, 256, 0, stream>>>(sbpos, nsb, cap);
    k_part<<<(nnz + CHUNK - 1) / CHUNK, 256, 0, stream>>>(rows, cols, vals, recTmp, sbpos, nnz, FLAG);
    k_sortsb<<<nsb, 1024, 0, stream>>>(recTmp, rec2, rstart, rend, sbpos, cap, n_rows);
}

extern "C" void kernel_launch(void* const* d_in, const int* in_sizes, int n_in,
                              void* d_out, int out_size, void* d_ws, size_t ws_size,
                              hipStream_t stream) {
    const int* users = (const int*)d_in[0];
    const int* pos   = (const int*)d_in[1];
    const int* neg   = (const int*)d_in[2];
    const int* adj_r = (const int*)d_in[3];
    const int* adj_c = (const int*)d_in[4];
    const void* adj_v = d_in[5];
    const int* ug_r  = (const int*)d_in[6];
    const int* ug_c  = (const int*)d_in[7];
    const void* ug_v = d_in[8];
    const int* ig_r  = (const int*)d_in[9];
    const int* ig_c  = (const int*)d_in[10];
    const void* ig_v = d_in[11];
    const void* ue   = d_in[12];
    const void* ie   = d_in[13];
    const void* Wgc  = d_in[14];
    const void* bgc  = d_in[15];
    const void* Wbi  = d_in[16];
    const void* bbi  = d_in[17];
    const void* Wu0  = d_in[18];
    const void* bu0  = d_in[19];
    const void* Wu1  = d_in[20];
    const void* bu1  = d_in[21];
    const void* Wi0  = d_in[22];
    const void* bi0  = d_in[23];
    const void* Wi1  = d_in[24];
    const void* bi1  = d_in[25];

    char* ws = (char*)d_ws;
    int*   FLAG  = (int*)(ws + 0);                       // 256 B
    float* T1    = (float*)(ws + 256);                   // 46,080,000 (fp32 NTOT*64)
    bf16*  ego16 = (bf16*)(ws + 46080256L);              // 23,040,000
    bf16*  UH    = (bf16*)(ws + 69120256L);              //  7,680,000
    bf16*  IH    = (bf16*)(ws + 76800256L);              // 15,360,000
    bf16*  NM1   = (bf16*)(ws + 92160256L);              // 23,040,000
    bf16*  NM2   = (bf16*)(ws + 115200256L);             // 23,040,000
    bf16*  NM3   = (bf16*)(ws + 138240256L);             // 23,040,000
    // T2 (bf16, <=15.36 MB) aliases NM2 region: dead before layer k=1 writes NM2
    bf16*  T2    = (bf16*)(ws + 115200256L);
    // recTmp aliases T1: builds finish before any SpMM writes T1 (adj needs 30.3 MB < 46 MB)
    uint2* recTmp = (uint2*)(ws + 256);
    uint2* rec2A = (uint2*)(ws + 161280256L);            // 88*43008*8 = 30,277,632
    uint2* rec2U = (uint2*)(ws + 191557888L);            // 30*34816*8 =  8,355,840
    uint2* rec2I = (uint2*)(ws + 199913728L);            // 59*34816*8 = 16,433,152
    int* rstartA = (int*)(ws + 216346880L);              //    720,000
    int* rendA   = (int*)(ws + 217066880L);              //    720,000
    int* rstartU = (int*)(ws + 217786880L);              //    240,000
    int* rendU   = (int*)(ws + 218026880L);              //    240,000
    int* rstartI = (int*)(ws + 218266880L);              //    480,000
    int* rendI   = (int*)(ws + 218746880L);              //    480,000
    int* sbpos   = (int*)(ws + 219226880L);              //      6,144 (96 x 64B lines)
                                                         // end 219,233,024 (< 261,120,256 proven)

    k_detect<<<1, 64, 0, stream>>>(adj_v, FLAG);
    k_cast16<<<45000, 256, 0, stream>>>(ue, ie, ego16, FLAG);

    // ---- two-level build of row-sorted packed records (recTmp aliases T1) ----
    build_graph(ug_r,  ug_c,  ug_v,  NNZ_UG,  NSB_UG,  CAPU_SB, N_USER,
                sbpos, recTmp, rec2U, rstartU, rendU, FLAG, stream);
    build_graph(ig_r,  ig_c,  ig_v,  NNZ_IG,  NSB_IG,  CAPI_SB, N_ITEM,
                sbpos, recTmp, rec2I, rstartI, rendI, FLAG, stream);
    build_graph(adj_r, adj_c, adj_v, NNZ_ADJ, NSB_ADJ, CAPA_SB, NTOT,
                sbpos, recTmp, rec2A, rstartA, rendA, FLAG, stream);

    // ---- user MLP branch ----
    k_spmm_bf<<<(N_USER + 31) / 32, 256, 0, stream>>>(rstartU, rendU, rec2U, ego16, T1, N_USER);
    k_gemm64<1><<<(N_USER + 255) / 256, 256, 0, stream>>>(T1, Wu0, bu0, T2, N_USER, FLAG);
    k_spmm_bf<<<(N_USER + 31) / 32, 256, 0, stream>>>(rstartU, rendU, rec2U, T2, T1, N_USER);
    k_gemm64<2><<<(N_USER + 255) / 256, 256, 0, stream>>>(T1, Wu1, bu1, UH, N_USER, FLAG);

    // ---- item MLP branch ----
    const bf16* ego16I = ego16 + (size_t)N_USER * 64;
    k_spmm_bf<<<(N_ITEM + 31) / 32, 256, 0, stream>>>(rstartI, rendI, rec2I, ego16I, T1, N_ITEM);
    k_gemm64<1><<<(N_ITEM + 255) / 256, 256, 0, stream>>>(T1, Wi0, bi0, T2, N_ITEM, FLAG);
    k_spmm_bf<<<(N_ITEM + 31) / 32, 256, 0, stream>>>(rstartI, rendI, rec2I, T2, T1, N_ITEM);
    k_gemm64<2><<<(N_ITEM + 255) / 256, 256, 0, stream>>>(T1, Wi1, bi1, IH, N_ITEM, FLAG);

    // ---- 3 NGCF layers (ego bf16 in place; norm fused) ----
    bf16* norms[3] = {NM1, NM2, NM3};
    for (int k = 0; k < 3; k++) {
        k_spmm_bf<<<(NTOT + 31) / 32, 256, 0, stream>>>(rstartA, rendA, rec2A, ego16, T1, NTOT);
        k_layer<<<(NTOT + 255) / 256, 256, 0, stream>>>(T1, ego16, Wgc, bgc, Wbi, bbi,
                                                        (long)k * 4096, (long)k * 64,
                                                        norms[k], NTOT, FLAG);
    }

    // ---- output gather ----
    k_gather<<<12288, 64, 0, stream>>>(users, pos, neg, ue, ie, NM1, NM2, NM3, UH, IH,
                                       d_out, FLAG);
}

// Round 10
// 1466.234 us; speedup vs baseline: 3.7544x; 3.7544x over previous
//
#include <hip/hip_runtime.h>
#include <hip/hip_bf16.h>

#define N_USER 60000
#define N_ITEM 120000
#define NTOT   180000
#define NNZ_ADJ 3600000
#define NNZ_UG   960000
#define NNZ_IG  1920000

#define RSB     2048        // rows per super-bin
#define NSB_ADJ ((NTOT  + RSB - 1) / RSB)   // 88
#define NSB_UG  ((N_USER+ RSB - 1) / RSB)   // 30
#define NSB_IG  ((N_ITEM+ RSB - 1) / RSB)   // 59
#define CAPA_SB 43008       // mean 40960 + 10 sigma
#define CAPU_SB 34816       // mean 32768 + 11 sigma
#define CAPI_SB 34816       // mean 32768 + 11 sigma
#define CHUNK   4096

typedef __hip_bfloat16 bf16;

// load float element i from input tensor of unknown dtype: flag=1 -> fp32, 0 -> bf16
__device__ __forceinline__ float ldf(const void* p, long i, int f) {
    return f ? ((const float*)p)[i] : __bfloat162float(((const bf16*)p)[i]);
}

// pack two fp32 -> one uint holding 2 bf16
__device__ __forceinline__ unsigned pk2(float a, float b) {
    unsigned short lo = __bfloat16_as_ushort(__float2bfloat16(a));
    unsigned short hi = __bfloat16_as_ushort(__float2bfloat16(b));
    return (unsigned)lo | ((unsigned)hi << 16);
}

// ---------------- dtype detector (adj_vals >= 0 -> bf16 words have bit15==0) ----
__global__ void k_detect(const void* __restrict__ vals, int* __restrict__ flag) {
    if (threadIdx.x == 0 && blockIdx.x == 0) {
        const unsigned short* w = (const unsigned short*)vals;
        int cnt = 0;
        for (int i = 0; i < 512; i += 2) cnt += (w[i] >> 15) & 1;
        *flag = (cnt > 16) ? 1 : 0;
    }
}

// ---------------- cast user/item emb -> ego bf16 ----------------
__global__ __launch_bounds__(256) void k_cast16(const void* __restrict__ ue,
                                                const void* __restrict__ ie,
                                                bf16* __restrict__ ego16,
                                                const int* __restrict__ flag) {
    int f = *flag;
    long i = (long)blockIdx.x * 256 + threadIdx.x;   // NTOT*64 = 11,520,000
    const long uN = (long)N_USER * 64;
    if (i < (long)NTOT * 64) {
        float v = (i < uN) ? ldf(ue, i, f) : ldf(ie, i - uN, f);
        ego16[i] = __float2bfloat16(v);
    }
}

// ================= two-level binned build =================
__global__ __launch_bounds__(256) void k_initpos(int* __restrict__ sbpos, int nsb, int cap) {
    int i = blockIdx.x * 256 + threadIdx.x;
    if (i < nsb) sbpos[i * 16] = i * cap;
}

// L1: partition edges into <=88 super-bins (2048 rows each).
// Record: {rl(11b)<<18 | col(18b), val_f32}
__global__ __launch_bounds__(256) void k_part(const int* __restrict__ rows,
                                              const int* __restrict__ cols,
                                              const void* __restrict__ vals,
                                              uint2* __restrict__ rec,
                                              int* __restrict__ sbpos,
                                              int nnz,
                                              const int* __restrict__ flag) {
    __shared__ int lcnt[96];
    __shared__ int lbase[96];
    int f = *flag;
    int t = threadIdx.x;
    int base = blockIdx.x * CHUNK;
    if (t < 96) lcnt[t] = 0;
    __syncthreads();
    for (int k = 0; k < CHUNK / 256; k++) {
        int e = base + k * 256 + t;
        if (e < nnz) atomicAdd(&lcnt[rows[e] >> 11], 1);
    }
    __syncthreads();
    if (t < 96) {
        int c = lcnt[t];
        lbase[t] = c ? atomicAdd(&sbpos[t * 16], c) : 0;
        lcnt[t] = 0;
    }
    __syncthreads();
    for (int k = 0; k < CHUNK / 256; k++) {
        int e = base + k * 256 + t;
        if (e < nnz) {
            int r = rows[e];
            int sb = r >> 11;
            int o = atomicAdd(&lcnt[sb], 1);
            unsigned meta = ((unsigned)(r & 2047) << 18) | (unsigned)cols[e];
            rec[lbase[sb] + o] = make_uint2(meta, __float_as_uint(ldf(vals, e, f)));
        }
    }
}

// L2: per-super-bin counting sort into row order; emits absolute [rstart, rend).
__global__ __launch_bounds__(1024) void k_sortsb(const uint2* __restrict__ rec,
                                                 uint2* __restrict__ rec2,
                                                 int* __restrict__ rstart,
                                                 int* __restrict__ rend,
                                                 const int* __restrict__ sbpos,
                                                 int cap, int n_rows) {
    __shared__ int cnt[RSB];
    __shared__ int pos[RSB];
    __shared__ int carry;
    int b = blockIdx.x, t = threadIdx.x;
    int s = b * cap;
    int e = sbpos[b * 16];           // final fill cursor
    cnt[t] = 0; cnt[t + 1024] = 0;
    if (t == 0) carry = 0;
    __syncthreads();
    for (int j = s + t; j < e; j += 1024)
        atomicAdd(&cnt[rec[j].x >> 18], 1);
    __syncthreads();
    for (int tile = 0; tile < 2; tile++) {
        int i = tile * 1024 + t;
        int v = cnt[i];
        pos[i] = v;
        __syncthreads();
        for (int d = 1; d < 1024; d <<= 1) {
            int w = (t >= d) ? pos[i - d] : 0;
            __syncthreads();
            if (t >= d) pos[i] += w;
            __syncthreads();
        }
        int inc = pos[i];            // inclusive within tile
        int ex  = carry + inc - v;   // exclusive global
        __syncthreads();
        pos[i] = ex;
        if (t == 1023) carry += inc;
        __syncthreads();
    }
    int row0 = b * RSB;
    for (int i = t; i < RSB; i += 1024) {
        int row = row0 + i;
        if (row < n_rows) {
            rstart[row] = s + pos[i];
            rend[row]   = s + pos[i] + cnt[i];
        }
    }
    __syncthreads();
    for (int j = s + t; j < e; j += 1024) {
        uint2 r = rec[j];
        int o = atomicAdd(&pos[r.x >> 18], 1);
        rec2[s + o] = r;
    }
}

// ================= CSR SpMM, bf16 x: one row per 8-lane octet =================
__global__ __launch_bounds__(256) void k_spmm_bf(const int* __restrict__ rstart,
                                                 const int* __restrict__ rend,
                                                 const uint2* __restrict__ rec,
                                                 const bf16* __restrict__ x,
                                                 float* __restrict__ out,
                                                 int n_rows) {
    int row = blockIdx.x * 32 + (threadIdx.x >> 3);
    int p = threadIdx.x & 7;
    if (row >= n_rows) return;
    int s = rstart[row], e = rend[row];
    const uint4* xb = (const uint4*)x;   // 8 bf16 per uint4
    float a[8];
#pragma unroll
    for (int i = 0; i < 8; i++) a[i] = 0.0f;
    for (int j = s; j < e; j++) {
        uint2 r = rec[j];
        int col = r.x & 0x3FFFF;
        float v = __uint_as_float(r.y);
        uint4 q = xb[(long)col * 8 + p];
        a[0] += v * __uint_as_float(q.x << 16);
        a[1] += v * __uint_as_float(q.x & 0xFFFF0000u);
        a[2] += v * __uint_as_float(q.y << 16);
        a[3] += v * __uint_as_float(q.y & 0xFFFF0000u);
        a[4] += v * __uint_as_float(q.z << 16);
        a[5] += v * __uint_as_float(q.z & 0xFFFF0000u);
        a[6] += v * __uint_as_float(q.w << 16);
        a[7] += v * __uint_as_float(q.w & 0xFFFF0000u);
    }
    float* o = out + (long)row * 64 + p * 8;
    *(float4*)(o + 0) = make_float4(a[0], a[1], a[2], a[3]);
    *(float4*)(o + 4) = make_float4(a[4], a[5], a[6], a[7]);
}

// ---------------- Y[M,64] = act(X[M,64] @ W[64,64] + b) -> bf16 ----------------
// ACT: 1 = elu, 2 = relu
// Thread PAIR per row: each thread owns 32 output cols -> acc[32] stays in
// registers (round-8/9 lesson: acc[64]/thread spills at the compiler's 64-VGPR
// budget; never take a pointer into a local array -- it forces scratch).
template <int ACT>
__global__ __launch_bounds__(256) void k_gemm64(const float* __restrict__ X,
                                                const void* __restrict__ W,
                                                const void* __restrict__ b,
                                                bf16* __restrict__ Y, int M,
                                                const int* __restrict__ flag) {
    __shared__ float Wl[64][64];
    __shared__ float bl[64];
    int f = *flag;
    int tid = threadIdx.x;
    for (int i = tid; i < 4096; i += 256) Wl[i >> 6][i & 63] = ldf(W, i, f);
    if (tid < 64) bl[tid] = ldf(b, tid, f);
    __syncthreads();

    int r = blockIdx.x * 128 + (tid >> 1);
    int jh = (tid & 1) * 32;          // column half
    if (r >= M) return;
    const float* xr = X + (long)r * 64;

    float acc[32];
#pragma unroll
    for (int j = 0; j < 32; j++) acc[j] = bl[jh + j];

    for (int k4 = 0; k4 < 64; k4 += 4) {
        float4 xv = *(const float4*)(xr + k4);
#pragma unroll
        for (int kk = 0; kk < 4; kk++) {
            float xs = (kk == 0) ? xv.x : (kk == 1) ? xv.y : (kk == 2) ? xv.z : xv.w;
#pragma unroll
            for (int j = 0; j < 32; j += 4) {
                float4 w4 = *(const float4*)&Wl[k4 + kk][jh + j];
                acc[j + 0] += xs * w4.x;
                acc[j + 1] += xs * w4.y;
                acc[j + 2] += xs * w4.z;
                acc[j + 3] += xs * w4.w;
            }
        }
    }

#pragma unroll
    for (int j = 0; j < 32; j++) {
        float v = acc[j];
        if (ACT == 2) v = fmaxf(v, 0.0f);
        else          v = (v > 0.0f) ? v : (expf(v) - 1.0f);
        acc[j] = v;
    }
    uint4* y = (uint4*)(Y + (long)r * 64 + jh);
#pragma unroll
    for (int q = 0; q < 4; q++) {
        y[q] = make_uint4(pk2(acc[q * 8 + 0], acc[q * 8 + 1]),
                          pk2(acc[q * 8 + 2], acc[q * 8 + 3]),
                          pk2(acc[q * 8 + 4], acc[q * 8 + 5]),
                          pk2(acc[q * 8 + 6], acc[q * 8 + 7]));
    }
}

// ---------------- fused NGCF layer + l2norm; ego bf16 updated IN PLACE --------
// Thread pair per row (see k_gemm64 note); __shfl_xor(ss,1) completes row norm.
__global__ __launch_bounds__(256) void k_layer(const float* __restrict__ S,
                                               bf16* __restrict__ E16,
                                               const void* __restrict__ Wgc,
                                               const void* __restrict__ bgc,
                                               const void* __restrict__ Wbi,
                                               const void* __restrict__ bbi,
                                               long woff, long boff,
                                               bf16* __restrict__ nm, int M,
                                               const int* __restrict__ flag) {
    __shared__ float W1[64][64];
    __shared__ float W2[64][64];
    __shared__ float bl[64];
    int f = *flag;
    int tid = threadIdx.x;
    for (int i = tid; i < 4096; i += 256) {
        W1[i >> 6][i & 63] = ldf(Wgc, woff + i, f);
        W2[i >> 6][i & 63] = ldf(Wbi, woff + i, f);
    }
    if (tid < 64) bl[tid] = ldf(bgc, boff + tid, f) + ldf(bbi, boff + tid, f);
    __syncthreads();

    int r = blockIdx.x * 128 + (tid >> 1);
    int jh = (tid & 1) * 32;          // column half
    if (r >= M) return;
    const float* sr = S + (long)r * 64;
    const uint2* ep = (const uint2*)(E16 + (long)r * 64);   // 4 bf16 per uint2

    float acc[32];
#pragma unroll
    for (int j = 0; j < 32; j++) acc[j] = bl[jh + j];

    for (int k4 = 0; k4 < 64; k4 += 4) {
        float4 sv = *(const float4*)(sr + k4);
        uint2 eq = ep[k4 >> 2];
        float e0 = __uint_as_float(eq.x << 16);
        float e1 = __uint_as_float(eq.x & 0xFFFF0000u);
        float e2 = __uint_as_float(eq.y << 16);
        float e3 = __uint_as_float(eq.y & 0xFFFF0000u);
#pragma unroll
        for (int kk = 0; kk < 4; kk++) {
            float xs = (kk == 0) ? sv.x : (kk == 1) ? sv.y : (kk == 2) ? sv.z : sv.w;
            float xe = ((kk == 0) ? e0 : (kk == 1) ? e1 : (kk == 2) ? e2 : e3) * xs;
#pragma unroll
            for (int j = 0; j < 32; j += 4) {
                float4 w1 = *(const float4*)&W1[k4 + kk][jh + j];
                float4 w2 = *(const float4*)&W2[k4 + kk][jh + j];
                acc[j + 0] += xs * w1.x + xe * w2.x;
                acc[j + 1] += xs * w1.y + xe * w2.y;
                acc[j + 2] += xs * w1.z + xe * w2.z;
                acc[j + 3] += xs * w1.w + xe * w2.w;
            }
        }
    }

    float ss = 0.0f;
#pragma unroll
    for (int j = 0; j < 32; j++) {
        float v = acc[j];
        v = (v > 0.0f) ? v : 0.2f * v;
        acc[j] = v;
        ss += v * v;
    }
    ss += __shfl_xor(ss, 1, 64);      // pair partner holds the other 32 cols
    float sc = 1.0f / fmaxf(sqrtf(ss), 1e-12f);

    uint4* er = (uint4*)(E16 + (long)r * 64 + jh);
    uint4* nr = (uint4*)(nm + (long)r * 64 + jh);
#pragma unroll
    for (int q = 0; q < 4; q++) {
        er[q] = make_uint4(pk2(acc[q * 8 + 0], acc[q * 8 + 1]),
                           pk2(acc[q * 8 + 2], acc[q * 8 + 3]),
                           pk2(acc[q * 8 + 4], acc[q * 8 + 5]),
                           pk2(acc[q * 8 + 6], acc[q * 8 + 7]));
        nr[q] = make_uint4(pk2(acc[q * 8 + 0] * sc, acc[q * 8 + 1] * sc),
                           pk2(acc[q * 8 + 2] * sc, acc[q * 8 + 3] * sc),
                           pk2(acc[q * 8 + 4] * sc, acc[q * 8 + 5] * sc),
                           pk2(acc[q * 8 + 6] * sc, acc[q * 8 + 7] * sc));
    }
}

// ---------------- final gather into output ----------------
__global__ __launch_bounds__(64) void k_gather(const int* __restrict__ users,
                                               const int* __restrict__ pos,
                                               const int* __restrict__ neg,
                                               const void* __restrict__ ue,
                                               const void* __restrict__ ie,
                                               const bf16* __restrict__ n1,
                                               const bf16* __restrict__ n2,
                                               const bf16* __restrict__ n3,
                                               const bf16* __restrict__ uh,
                                               const bf16* __restrict__ ih,
                                               void* __restrict__ out,
                                               const int* __restrict__ flag) {
    int f = *flag;
    int b = blockIdx.x;           // 0..12287: [users | pos | neg] x 4096
    int which = b >> 12;
    int s = b & 4095;
    int lane = threadIdx.x;       // 64
    long ebase, nbase;
    const void* e0;
    const bf16* hh;
    if (which == 0) {
        int r = users[s];
        e0 = ue; ebase = (long)r * 64;
        hh = uh + (long)r * 64;
        nbase = (long)r * 64;
    } else {
        int r = (which == 1) ? pos[s] : neg[s];
        e0 = ie; ebase = (long)r * 64;
        hh = ih + (long)r * 64;
        nbase = (long)(N_USER + r) * 64;
    }
    float o0 = ldf(e0, ebase + lane, f);
    float o1 = __bfloat162float(n1[nbase + lane]);
    float o2 = __bfloat162float(n2[nbase + lane]);
    float o3 = __bfloat162float(n3[nbase + lane]);
    float o4 = __bfloat162float(hh[lane]);
    long ob = (long)b * 320;
    if (f) {
        float* o = (float*)out + ob;
        o[lane] = o0; o[64 + lane] = o1; o[128 + lane] = o2;
        o[192 + lane] = o3; o[256 + lane] = o4;
    } else {
        bf16* o = (bf16*)out + ob;
        o[lane]       = __float2bfloat16(o0);
        o[64 + lane]  = __float2bfloat16(o1);
        o[128 + lane] = __float2bfloat16(o2);
        o[192 + lane] = __float2bfloat16(o3);
        o[256 + lane] = __float2bfloat16(o4);
    }
}

// host-side helper: two-level build of row-sorted packed records for one graph
static void build_graph(const int* rows, const int* cols, const void* vals,
                        int nnz, int nsb, int cap, int n_rows,
                        int* sbpos, uint2* recTmp, uint2* rec2,
                        int* rstart, int* rend,
                        const int* FLAG, hipStream_t stream) {
    k_initpos<<<1, 256, 0, stream>>>(sbpos, nsb, cap);
    k_part<<<(nnz + CHUNK - 1) / CHUNK, 256, 0, stream>>>(rows, cols, vals, recTmp, sbpos, nnz, FLAG);
    k_sortsb<<<nsb, 1024, 0, stream>>>(recTmp, rec2, rstart, rend, sbpos, cap, n_rows);
}

extern "C" void kernel_launch(void* const* d_in, const int* in_sizes, int n_in,
                              void* d_out, int out_size, void* d_ws, size_t ws_size,
                              hipStream_t stream) {
    const int* users = (const int*)d_in[0];
    const int* pos   = (const int*)d_in[1];
    const int* neg   = (const int*)d_in[2];
    const int* adj_r = (const int*)d_in[3];
    const int* adj_c = (const int*)d_in[4];
    const void* adj_v = d_in[5];
    const int* ug_r  = (const int*)d_in[6];
    const int* ug_c  = (const int*)d_in[7];
    const void* ug_v = d_in[8];
    const int* ig_r  = (const int*)d_in[9];
    const int* ig_c  = (const int*)d_in[10];
    const void* ig_v = d_in[11];
    const void* ue   = d_in[12];
    const void* ie   = d_in[13];
    const void* Wgc  = d_in[14];
    const void* bgc  = d_in[15];
    const void* Wbi  = d_in[16];
    const void* bbi  = d_in[17];
    const void* Wu0  = d_in[18];
    const void* bu0  = d_in[19];
    const void* Wu1  = d_in[20];
    const void* bu1  = d_in[21];
    const void* Wi0  = d_in[22];
    const void* bi0  = d_in[23];
    const void* Wi1  = d_in[24];
    const void* bi1  = d_in[25];

    char* ws = (char*)d_ws;
    int*   FLAG  = (int*)(ws + 0);                       // 256 B
    float* T1    = (float*)(ws + 256);                   // 46,080,000 (fp32 NTOT*64)
    bf16*  ego16 = (bf16*)(ws + 46080256L);              // 23,040,000
    bf16*  UH    = (bf16*)(ws + 69120256L);              //  7,680,000
    bf16*  IH    = (bf16*)(ws + 76800256L);              // 15,360,000
    bf16*  NM1   = (bf16*)(ws + 92160256L);              // 23,040,000
    bf16*  NM2   = (bf16*)(ws + 115200256L);             // 23,040,000
    bf16*  NM3   = (bf16*)(ws + 138240256L);             // 23,040,000
    // T2 (bf16, <=15.36 MB) aliases NM2 region: dead before layer k=1 writes NM2
    bf16*  T2    = (bf16*)(ws + 115200256L);
    // recTmp aliases T1: builds finish before any SpMM writes T1 (adj needs 30.3 MB < 46 MB)
    uint2* recTmp = (uint2*)(ws + 256);
    uint2* rec2A = (uint2*)(ws + 161280256L);            // 88*43008*8 = 30,277,632
    uint2* rec2U = (uint2*)(ws + 191557888L);            // 30*34816*8 =  8,355,840
    uint2* rec2I = (uint2*)(ws + 199913728L);            // 59*34816*8 = 16,433,152
    int* rstartA = (int*)(ws + 216346880L);              //    720,000
    int* rendA   = (int*)(ws + 217066880L);              //    720,000
    int* rstartU = (int*)(ws + 217786880L);              //    240,000
    int* rendU   = (int*)(ws + 218026880L);              //    240,000
    int* rstartI = (int*)(ws + 218266880L);              //    480,000
    int* rendI   = (int*)(ws + 218746880L);              //    480,000
    int* sbpos   = (int*)(ws + 219226880L);              //      6,144 (96 x 64B lines)
                                                         // end 219,233,024 (< 261,120,256 proven)

    k_detect<<<1, 64, 0, stream>>>(adj_v, FLAG);
    k_cast16<<<45000, 256, 0, stream>>>(ue, ie, ego16, FLAG);

    // ---- two-level build of row-sorted packed records (recTmp aliases T1) ----
    build_graph(ug_r,  ug_c,  ug_v,  NNZ_UG,  NSB_UG,  CAPU_SB, N_USER,
                sbpos, recTmp, rec2U, rstartU, rendU, FLAG, stream);
    build_graph(ig_r,  ig_c,  ig_v,  NNZ_IG,  NSB_IG,  CAPI_SB, N_ITEM,
                sbpos, recTmp, rec2I, rstartI, rendI, FLAG, stream);
    build_graph(adj_r, adj_c, adj_v, NNZ_ADJ, NSB_ADJ, CAPA_SB, NTOT,
                sbpos, recTmp, rec2A, rstartA, rendA, FLAG, stream);

    // ---- user MLP branch ----
    k_spmm_bf<<<(N_USER + 31) / 32, 256, 0, stream>>>(rstartU, rendU, rec2U, ego16, T1, N_USER);
    k_gemm64<1><<<(N_USER + 127) / 128, 256, 0, stream>>>(T1, Wu0, bu0, T2, N_USER, FLAG);
    k_spmm_bf<<<(N_USER + 31) / 32, 256, 0, stream>>>(rstartU, rendU, rec2U, T2, T1, N_USER);
    k_gemm64<2><<<(N_USER + 127) / 128, 256, 0, stream>>>(T1, Wu1, bu1, UH, N_USER, FLAG);

    // ---- item MLP branch ----
    const bf16* ego16I = ego16 + (size_t)N_USER * 64;
    k_spmm_bf<<<(N_ITEM + 31) / 32, 256, 0, stream>>>(rstartI, rendI, rec2I, ego16I, T1, N_ITEM);
    k_gemm64<1><<<(N_ITEM + 127) / 128, 256, 0, stream>>>(T1, Wi0, bi0, T2, N_ITEM, FLAG);
    k_spmm_bf<<<(N_ITEM + 31) / 32, 256, 0, stream>>>(rstartI, rendI, rec2I, T2, T1, N_ITEM);
    k_gemm64<2><<<(N_ITEM + 127) / 128, 256, 0, stream>>>(T1, Wi1, bi1, IH, N_ITEM, FLAG);

    // ---- 3 NGCF layers (ego bf16 in place; norm fused) ----
    bf16* norms[3] = {NM1, NM2, NM3};
    for (int k = 0; k < 3; k++) {
        k_spmm_bf<<<(NTOT + 31) / 32, 256, 0, stream>>>(rstartA, rendA, rec2A, ego16, T1, NTOT);
        k_layer<<<(NTOT + 127) / 128, 256, 0, stream>>>(T1, ego16, Wgc, bgc, Wbi, bbi,
                                                        (long)k * 4096, (long)k * 64,
                                                        norms[k], NTOT, FLAG);
    }

    // ---- output gather ----
    k_gather<<<12288, 64, 0, stream>>>(users, pos, neg, ue, ie, NM1, NM2, NM3, UH, IH,
                                       d_out, FLAG);
}

// Round 11
// 1291.788 us; speedup vs baseline: 4.2614x; 1.1350x over previous
//
#include <hip/hip_runtime.h>
#include <hip/hip_bf16.h>

#define N_USER 60000
#define N_ITEM 120000
#define NTOT   180000
#define NNZ_ADJ 3600000
#define NNZ_UG   960000
#define NNZ_IG  1920000

#define RSB     2048        // rows per super-bin
#define NSB_ADJ ((NTOT  + RSB - 1) / RSB)   // 88
#define NSB_UG  ((N_USER+ RSB - 1) / RSB)   // 30
#define NSB_IG  ((N_ITEM+ RSB - 1) / RSB)   // 59
#define CAPA_SB 43008       // mean 40960 + 10 sigma
#define CAPU_SB 34816       // mean 32768 + 11 sigma
#define CAPI_SB 34816       // mean 32768 + 11 sigma
#define CHUNK   4096

typedef __hip_bfloat16 bf16;

// load float element i from input tensor of unknown dtype: flag=1 -> fp32, 0 -> bf16
__device__ __forceinline__ float ldf(const void* p, long i, int f) {
    return f ? ((const float*)p)[i] : __bfloat162float(((const bf16*)p)[i]);
}

// pack two fp32 -> one uint holding 2 bf16
__device__ __forceinline__ unsigned pk2(float a, float b) {
    unsigned short lo = __bfloat16_as_ushort(__float2bfloat16(a));
    unsigned short hi = __bfloat16_as_ushort(__float2bfloat16(b));
    return (unsigned)lo | ((unsigned)hi << 16);
}

__device__ __forceinline__ float getc(float4 v, int kk) {
    return (kk == 0) ? v.x : (kk == 1) ? v.y : (kk == 2) ? v.z : v.w;
}

// ---------------- dtype detector (adj_vals >= 0 -> bf16 words have bit15==0) ----
__global__ void k_detect(const void* __restrict__ vals, int* __restrict__ flag) {
    if (threadIdx.x == 0 && blockIdx.x == 0) {
        const unsigned short* w = (const unsigned short*)vals;
        int cnt = 0;
        for (int i = 0; i < 512; i += 2) cnt += (w[i] >> 15) & 1;
        *flag = (cnt > 16) ? 1 : 0;
    }
}

// ---------------- cast user/item emb -> ego bf16 ----------------
__global__ __launch_bounds__(256) void k_cast16(const void* __restrict__ ue,
                                                const void* __restrict__ ie,
                                                bf16* __restrict__ ego16,
                                                const int* __restrict__ flag) {
    int f = *flag;
    long i = (long)blockIdx.x * 256 + threadIdx.x;   // NTOT*64 = 11,520,000
    const long uN = (long)N_USER * 64;
    if (i < (long)NTOT * 64) {
        float v = (i < uN) ? ldf(ue, i, f) : ldf(ie, i - uN, f);
        ego16[i] = __float2bfloat16(v);
    }
}

// ================= two-level binned build =================
__global__ __launch_bounds__(256) void k_initpos(int* __restrict__ sbpos, int nsb, int cap) {
    int i = blockIdx.x * 256 + threadIdx.x;
    if (i < nsb) sbpos[i * 16] = i * cap;
}

// L1: partition edges into <=88 super-bins (2048 rows each).
// Record: {rl(11b)<<18 | col(18b), val_f32}
__global__ __launch_bounds__(256) void k_part(const int* __restrict__ rows,
                                              const int* __restrict__ cols,
                                              const void* __restrict__ vals,
                                              uint2* __restrict__ rec,
                                              int* __restrict__ sbpos,
                                              int nnz,
                                              const int* __restrict__ flag) {
    __shared__ int lcnt[96];
    __shared__ int lbase[96];
    int f = *flag;
    int t = threadIdx.x;
    int base = blockIdx.x * CHUNK;
    if (t < 96) lcnt[t] = 0;
    __syncthreads();
    for (int k = 0; k < CHUNK / 256; k++) {
        int e = base + k * 256 + t;
        if (e < nnz) atomicAdd(&lcnt[rows[e] >> 11], 1);
    }
    __syncthreads();
    if (t < 96) {
        int c = lcnt[t];
        lbase[t] = c ? atomicAdd(&sbpos[t * 16], c) : 0;
        lcnt[t] = 0;
    }
    __syncthreads();
    for (int k = 0; k < CHUNK / 256; k++) {
        int e = base + k * 256 + t;
        if (e < nnz) {
            int r = rows[e];
            int sb = r >> 11;
            int o = atomicAdd(&lcnt[sb], 1);
            unsigned meta = ((unsigned)(r & 2047) << 18) | (unsigned)cols[e];
            rec[lbase[sb] + o] = make_uint2(meta, __float_as_uint(ldf(vals, e, f)));
        }
    }
}

// L2: per-super-bin counting sort into row order; emits absolute [rstart, rend).
__global__ __launch_bounds__(1024) void k_sortsb(const uint2* __restrict__ rec,
                                                 uint2* __restrict__ rec2,
                                                 int* __restrict__ rstart,
                                                 int* __restrict__ rend,
                                                 const int* __restrict__ sbpos,
                                                 int cap, int n_rows) {
    __shared__ int cnt[RSB];
    __shared__ int pos[RSB];
    __shared__ int carry;
    int b = blockIdx.x, t = threadIdx.x;
    int s = b * cap;
    int e = sbpos[b * 16];           // final fill cursor
    cnt[t] = 0; cnt[t + 1024] = 0;
    if (t == 0) carry = 0;
    __syncthreads();
    for (int j = s + t; j < e; j += 1024)
        atomicAdd(&cnt[rec[j].x >> 18], 1);
    __syncthreads();
    for (int tile = 0; tile < 2; tile++) {
        int i = tile * 1024 + t;
        int v = cnt[i];
        pos[i] = v;
        __syncthreads();
        for (int d = 1; d < 1024; d <<= 1) {
            int w = (t >= d) ? pos[i - d] : 0;
            __syncthreads();
            if (t >= d) pos[i] += w;
            __syncthreads();
        }
        int inc = pos[i];            // inclusive within tile
        int ex  = carry + inc - v;   // exclusive global
        __syncthreads();
        pos[i] = ex;
        if (t == 1023) carry += inc;
        __syncthreads();
    }
    int row0 = b * RSB;
    for (int i = t; i < RSB; i += 1024) {
        int row = row0 + i;
        if (row < n_rows) {
            rstart[row] = s + pos[i];
            rend[row]   = s + pos[i] + cnt[i];
        }
    }
    __syncthreads();
    for (int j = s + t; j < e; j += 1024) {
        uint2 r = rec[j];
        int o = atomicAdd(&pos[r.x >> 18], 1);
        rec2[s + o] = r;
    }
}

// ================= CSR SpMM, bf16 x: one row per 8-lane octet =================
__global__ __launch_bounds__(256) void k_spmm_bf(const int* __restrict__ rstart,
                                                 const int* __restrict__ rend,
                                                 const uint2* __restrict__ rec,
                                                 const bf16* __restrict__ x,
                                                 float* __restrict__ out,
                                                 int n_rows) {
    int row = blockIdx.x * 32 + (threadIdx.x >> 3);
    int p = threadIdx.x & 7;
    if (row >= n_rows) return;
    int s = rstart[row], e = rend[row];
    const uint4* xb = (const uint4*)x;   // 8 bf16 per uint4
    float a[8];
#pragma unroll
    for (int i = 0; i < 8; i++) a[i] = 0.0f;
    for (int j = s; j < e; j++) {
        uint2 r = rec[j];
        int col = r.x & 0x3FFFF;
        float v = __uint_as_float(r.y);
        uint4 q = xb[(long)col * 8 + p];
        a[0] += v * __uint_as_float(q.x << 16);
        a[1] += v * __uint_as_float(q.x & 0xFFFF0000u);
        a[2] += v * __uint_as_float(q.y << 16);
        a[3] += v * __uint_as_float(q.y & 0xFFFF0000u);
        a[4] += v * __uint_as_float(q.z << 16);
        a[5] += v * __uint_as_float(q.z & 0xFFFF0000u);
        a[6] += v * __uint_as_float(q.w << 16);
        a[7] += v * __uint_as_float(q.w & 0xFFFF0000u);
    }
    float* o = out + (long)row * 64 + p * 8;
    *(float4*)(o + 0) = make_float4(a[0], a[1], a[2], a[3]);
    *(float4*)(o + 4) = make_float4(a[4], a[5], a[6], a[7]);
}

// ---------------- Y[M,64] = act(X[M,64] @ W[64,64] + b) -> bf16 ----------------
// 4 rows x 8 cols per thread: each LDS W read (b128) feeds 16 FMAs (round-10
// lesson: at 1 row/thread the kernel is ds_read-throughput-bound, ~4 FMA/read).
// acc[4][8]=32 regs, all indices compile-time; NEVER take a pointer into acc.
template <int ACT>
__global__ __launch_bounds__(256) void k_gemm64(const float* __restrict__ X,
                                                const void* __restrict__ W,
                                                const void* __restrict__ b,
                                                bf16* __restrict__ Y, int M,
                                                const int* __restrict__ flag) {
    __shared__ float Wl[64][64];
    __shared__ float bl[64];
    int f = *flag;
    int tid = threadIdx.x;
    for (int i = tid; i < 4096; i += 256) Wl[i >> 6][i & 63] = ldf(W, i, f);
    if (tid < 64) bl[tid] = ldf(b, tid, f);
    __syncthreads();

    int lane = tid & 63;
    int wv = tid >> 6;              // wave 0..3
    int cg = lane & 7;              // column group -> cols [cg*8, cg*8+8)
    int ro = lane >> 3;             // row offset 0..7
    int jh = cg * 8;
    int rbase = blockIdx.x * 128 + wv * 32 + ro;    // rows rbase + 8*i

    bool rv[4];
    long ra[4];
#pragma unroll
    for (int i = 0; i < 4; i++) {
        int r = rbase + 8 * i;
        rv[i] = r < M;
        ra[i] = (long)(rv[i] ? r : M - 1) * 64;     // clamp loads, guard stores
    }

    float acc[4][8];
#pragma unroll
    for (int i = 0; i < 4; i++)
#pragma unroll
        for (int j = 0; j < 8; j++) acc[i][j] = bl[jh + j];

    for (int k4 = 0; k4 < 64; k4 += 4) {
        float4 sv[4];
#pragma unroll
        for (int i = 0; i < 4; i++) sv[i] = *(const float4*)(X + ra[i] + k4);
#pragma unroll
        for (int kk = 0; kk < 4; kk++) {
            float4 wa = *(const float4*)&Wl[k4 + kk][jh];
            float4 wb = *(const float4*)&Wl[k4 + kk][jh + 4];
#pragma unroll
            for (int i = 0; i < 4; i++) {
                float xs = getc(sv[i], kk);
                acc[i][0] += xs * wa.x;
                acc[i][1] += xs * wa.y;
                acc[i][2] += xs * wa.z;
                acc[i][3] += xs * wa.w;
                acc[i][4] += xs * wb.x;
                acc[i][5] += xs * wb.y;
                acc[i][6] += xs * wb.z;
                acc[i][7] += xs * wb.w;
            }
        }
    }

#pragma unroll
    for (int i = 0; i < 4; i++) {
#pragma unroll
        for (int j = 0; j < 8; j++) {
            float v = acc[i][j];
            if (ACT == 2) v = fmaxf(v, 0.0f);
            else          v = (v > 0.0f) ? v : (expf(v) - 1.0f);
            acc[i][j] = v;
        }
        if (rv[i]) {
            *(uint4*)(Y + ra[i] + jh) =
                make_uint4(pk2(acc[i][0], acc[i][1]), pk2(acc[i][2], acc[i][3]),
                           pk2(acc[i][4], acc[i][5]), pk2(acc[i][6], acc[i][7]));
        }
    }
}

// ---------------- fused NGCF layer + l2norm; ego bf16 updated IN PLACE --------
// Same 4-rows-x-8-cols structure as k_gemm64 (16 FMAs per W b128 read);
// row norm completed via shfl_xor 1/2/4 across the 8 column groups.
__global__ __launch_bounds__(256) void k_layer(const float* __restrict__ S,
                                               bf16* __restrict__ E16,
                                               const void* __restrict__ Wgc,
                                               const void* __restrict__ bgc,
                                               const void* __restrict__ Wbi,
                                               const void* __restrict__ bbi,
                                               long woff, long boff,
                                               bf16* __restrict__ nm, int M,
                                               const int* __restrict__ flag) {
    __shared__ float W1[64][64];
    __shared__ float W2[64][64];
    __shared__ float bl[64];
    int f = *flag;
    int tid = threadIdx.x;
    for (int i = tid; i < 4096; i += 256) {
        W1[i >> 6][i & 63] = ldf(Wgc, woff + i, f);
        W2[i >> 6][i & 63] = ldf(Wbi, woff + i, f);
    }
    if (tid < 64) bl[tid] = ldf(bgc, boff + tid, f) + ldf(bbi, boff + tid, f);
    __syncthreads();

    int lane = tid & 63;
    int wv = tid >> 6;
    int cg = lane & 7;
    int ro = lane >> 3;
    int jh = cg * 8;
    int rbase = blockIdx.x * 128 + wv * 32 + ro;

    bool rv[4];
    long ra[4];
#pragma unroll
    for (int i = 0; i < 4; i++) {
        int r = rbase + 8 * i;
        rv[i] = r < M;
        ra[i] = (long)(rv[i] ? r : M - 1) * 64;
    }

    float acc[4][8];
#pragma unroll
    for (int i = 0; i < 4; i++)
#pragma unroll
        for (int j = 0; j < 8; j++) acc[i][j] = bl[jh + j];

    for (int k4 = 0; k4 < 64; k4 += 4) {
        float4 sv[4];
        float ev[4][4];
#pragma unroll
        for (int i = 0; i < 4; i++) {
            sv[i] = *(const float4*)(S + ra[i] + k4);
            uint2 eq = *(const uint2*)(E16 + ra[i] + k4);
            ev[i][0] = __uint_as_float(eq.x << 16);
            ev[i][1] = __uint_as_float(eq.x & 0xFFFF0000u);
            ev[i][2] = __uint_as_float(eq.y << 16);
            ev[i][3] = __uint_as_float(eq.y & 0xFFFF0000u);
        }
#pragma unroll
        for (int kk = 0; kk < 4; kk++) {
            float4 w1a = *(const float4*)&W1[k4 + kk][jh];
            float4 w1b = *(const float4*)&W1[k4 + kk][jh + 4];
            float4 w2a = *(const float4*)&W2[k4 + kk][jh];
            float4 w2b = *(const float4*)&W2[k4 + kk][jh + 4];
#pragma unroll
            for (int i = 0; i < 4; i++) {
                float xs = getc(sv[i], kk);
                float xe = ev[i][kk] * xs;
                acc[i][0] += xs * w1a.x + xe * w2a.x;
                acc[i][1] += xs * w1a.y + xe * w2a.y;
                acc[i][2] += xs * w1a.z + xe * w2a.z;
                acc[i][3] += xs * w1a.w + xe * w2a.w;
                acc[i][4] += xs * w1b.x + xe * w2b.x;
                acc[i][5] += xs * w1b.y + xe * w2b.y;
                acc[i][6] += xs * w1b.z + xe * w2b.z;
                acc[i][7] += xs * w1b.w + xe * w2b.w;
            }
        }
    }

#pragma unroll
    for (int i = 0; i < 4; i++) {
        float ss = 0.0f;
#pragma unroll
        for (int j = 0; j < 8; j++) {
            float v = acc[i][j];
            v = (v > 0.0f) ? v : 0.2f * v;
            acc[i][j] = v;
            ss += v * v;
        }
        ss += __shfl_xor(ss, 1, 64);   // reduce across the 8 column groups
        ss += __shfl_xor(ss, 2, 64);
        ss += __shfl_xor(ss, 4, 64);
        float sc = 1.0f / fmaxf(sqrtf(ss), 1e-12f);
        if (rv[i]) {
            *(uint4*)(E16 + ra[i] + jh) =
                make_uint4(pk2(acc[i][0], acc[i][1]), pk2(acc[i][2], acc[i][3]),
                           pk2(acc[i][4], acc[i][5]), pk2(acc[i][6], acc[i][7]));
            *(uint4*)(nm + ra[i] + jh) =
                make_uint4(pk2(acc[i][0] * sc, acc[i][1] * sc),
                           pk2(acc[i][2] * sc, acc[i][3] * sc),
                           pk2(acc[i][4] * sc, acc[i][5] * sc),
                           pk2(acc[i][6] * sc, acc[i][7] * sc));
        }
    }
}

// ---------------- final gather into output ----------------
__global__ __launch_bounds__(64) void k_gather(const int* __restrict__ users,
                                               const int* __restrict__ pos,
                                               const int* __restrict__ neg,
                                               const void* __restrict__ ue,
                                               const void* __restrict__ ie,
                                               const bf16* __restrict__ n1,
                                               const bf16* __restrict__ n2,
                                               const bf16* __restrict__ n3,
                                               const bf16* __restrict__ uh,
                                               const bf16* __restrict__ ih,
                                               void* __restrict__ out,
                                               const int* __restrict__ flag) {
    int f = *flag;
    int b = blockIdx.x;           // 0..12287: [users | pos | neg] x 4096
    int which = b >> 12;
    int s = b & 4095;
    int lane = threadIdx.x;       // 64
    long ebase, nbase;
    const void* e0;
    const bf16* hh;
    if (which == 0) {
        int r = users[s];
        e0 = ue; ebase = (long)r * 64;
        hh = uh + (long)r * 64;
        nbase = (long)r * 64;
    } else {
        int r = (which == 1) ? pos[s] : neg[s];
        e0 = ie; ebase = (long)r * 64;
        hh = ih + (long)r * 64;
        nbase = (long)(N_USER + r) * 64;
    }
    float o0 = ldf(e0, ebase + lane, f);
    float o1 = __bfloat162float(n1[nbase + lane]);
    float o2 = __bfloat162float(n2[nbase + lane]);
    float o3 = __bfloat162float(n3[nbase + lane]);
    float o4 = __bfloat162float(hh[lane]);
    long ob = (long)b * 320;
    if (f) {
        float* o = (float*)out + ob;
        o[lane] = o0; o[64 + lane] = o1; o[128 + lane] = o2;
        o[192 + lane] = o3; o[256 + lane] = o4;
    } else {
        bf16* o = (bf16*)out + ob;
        o[lane]       = __float2bfloat16(o0);
        o[64 + lane]  = __float2bfloat16(o1);
        o[128 + lane] = __float2bfloat16(o2);
        o[192 + lane] = __float2bfloat16(o3);
        o[256 + lane] = __float2bfloat16(o4);
    }
}

// host-side helper: two-level build of row-sorted packed records for one graph
static void build_graph(const int* rows, const int* cols, const void* vals,
                        int nnz, int nsb, int cap, int n_rows,
                        int* sbpos, uint2* recTmp, uint2* rec2,
                        int* rstart, int* rend,
                        const int* FLAG, hipStream_t stream) {
    k_initpos<<<1, 256, 0, stream>>>(sbpos, nsb, cap);
    k_part<<<(nnz + CHUNK - 1) / CHUNK, 256, 0, stream>>>(rows, cols, vals, recTmp, sbpos, nnz, FLAG);
    k_sortsb<<<nsb, 1024, 0, stream>>>(recTmp, rec2, rstart, rend, sbpos, cap, n_rows);
}

extern "C" void kernel_launch(void* const* d_in, const int* in_sizes, int n_in,
                              void* d_out, int out_size, void* d_ws, size_t ws_size,
                              hipStream_t stream) {
    const int* users = (const int*)d_in[0];
    const int* pos   = (const int*)d_in[1];
    const int* neg   = (const int*)d_in[2];
    const int* adj_r = (const int*)d_in[3];
    const int* adj_c = (const int*)d_in[4];
    const void* adj_v = d_in[5];
    const int* ug_r  = (const int*)d_in[6];
    const int* ug_c  = (const int*)d_in[7];
    const void* ug_v = d_in[8];
    const int* ig_r  = (const int*)d_in[9];
    const int* ig_c  = (const int*)d_in[10];
    const void* ig_v = d_in[11];
    const void* ue   = d_in[12];
    const void* ie   = d_in[13];
    const void* Wgc  = d_in[14];
    const void* bgc  = d_in[15];
    const void* Wbi  = d_in[16];
    const void* bbi  = d_in[17];
    const void* Wu0  = d_in[18];
    const void* bu0  = d_in[19];
    const void* Wu1  = d_in[20];
    const void* bu1  = d_in[21];
    const void* Wi0  = d_in[22];
    const void* bi0  = d_in[23];
    const void* Wi1  = d_in[24];
    const void* bi1  = d_in[25];

    char* ws = (char*)d_ws;
    int*   FLAG  = (int*)(ws + 0);                       // 256 B
    float* T1    = (float*)(ws + 256);                   // 46,080,000 (fp32 NTOT*64)
    bf16*  ego16 = (bf16*)(ws + 46080256L);              // 23,040,000
    bf16*  UH    = (bf16*)(ws + 69120256L);              //  7,680,000
    bf16*  IH    = (bf16*)(ws + 76800256L);              // 15,360,000
    bf16*  NM1   = (bf16*)(ws + 92160256L);              // 23,040,000
    bf16*  NM2   = (bf16*)(ws + 115200256L);             // 23,040,000
    bf16*  NM3   = (bf16*)(ws + 138240256L);             // 23,040,000
    // T2 (bf16, <=15.36 MB) aliases NM2 region: dead before layer k=1 writes NM2
    bf16*  T2    = (bf16*)(ws + 115200256L);
    // recTmp aliases T1: builds finish before any SpMM writes T1 (adj needs 30.3 MB < 46 MB)
    uint2* recTmp = (uint2*)(ws + 256);
    uint2* rec2A = (uint2*)(ws + 161280256L);            // 88*43008*8 = 30,277,632
    uint2* rec2U = (uint2*)(ws + 191557888L);            // 30*34816*8 =  8,355,840
    uint2* rec2I = (uint2*)(ws + 199913728L);            // 59*34816*8 = 16,433,152
    int* rstartA = (int*)(ws + 216346880L);              //    720,000
    int* rendA   = (int*)(ws + 217066880L);              //    720,000
    int* rstartU = (int*)(ws + 217786880L);              //    240,000
    int* rendU   = (int*)(ws + 218026880L);              //    240,000
    int* rstartI = (int*)(ws + 218266880L);              //    480,000
    int* rendI   = (int*)(ws + 218746880L);              //    480,000
    int* sbpos   = (int*)(ws + 219226880L);              //      6,144 (96 x 64B lines)
                                                         // end 219,233,024 (< 261,120,256 proven)

    k_detect<<<1, 64, 0, stream>>>(adj_v, FLAG);
    k_cast16<<<45000, 256, 0, stream>>>(ue, ie, ego16, FLAG);

    // ---- two-level build of row-sorted packed records (recTmp aliases T1) ----
    build_graph(ug_r,  ug_c,  ug_v,  NNZ_UG,  NSB_UG,  CAPU_SB, N_USER,
                sbpos, recTmp, rec2U, rstartU, rendU, FLAG, stream);
    build_graph(ig_r,  ig_c,  ig_v,  NNZ_IG,  NSB_IG,  CAPI_SB, N_ITEM,
                sbpos, recTmp, rec2I, rstartI, rendI, FLAG, stream);
    build_graph(adj_r, adj_c, adj_v, NNZ_ADJ, NSB_ADJ, CAPA_SB, NTOT,
                sbpos, recTmp, rec2A, rstartA, rendA, FLAG, stream);

    // ---- user MLP branch ----
    k_spmm_bf<<<(N_USER + 31) / 32, 256, 0, stream>>>(rstartU, rendU, rec2U, ego16, T1, N_USER);
    k_gemm64<1><<<(N_USER + 127) / 128, 256, 0, stream>>>(T1, Wu0, bu0, T2, N_USER, FLAG);
    k_spmm_bf<<<(N_USER + 31) / 32, 256, 0, stream>>>(rstartU, rendU, rec2U, T2, T1, N_USER);
    k_gemm64<2><<<(N_USER + 127) / 128, 256, 0, stream>>>(T1, Wu1, bu1, UH, N_USER, FLAG);

    // ---- item MLP branch ----
    const bf16* ego16I = ego16 + (size_t)N_USER * 64;
    k_spmm_bf<<<(N_ITEM + 31) / 32, 256, 0, stream>>>(rstartI, rendI, rec2I, ego16I, T1, N_ITEM);
    k_gemm64<1><<<(N_ITEM + 127) / 128, 256, 0, stream>>>(T1, Wi0, bi0, T2, N_ITEM, FLAG);
    k_spmm_bf<<<(N_ITEM + 31) / 32, 256, 0, stream>>>(rstartI, rendI, rec2I, T2, T1, N_ITEM);
    k_gemm64<2><<<(N_ITEM + 127) / 128, 256, 0, stream>>>(T1, Wi1, bi1, IH, N_ITEM, FLAG);

    // ---- 3 NGCF layers (ego bf16 in place; norm fused) ----
    bf16* norms[3] = {NM1, NM2, NM3};
    for (int k = 0; k < 3; k++) {
        k_spmm_bf<<<(NTOT + 31) / 32, 256, 0, stream>>>(rstartA, rendA, rec2A, ego16, T1, NTOT);
        k_layer<<<(NTOT + 127) / 128, 256, 0, stream>>>(T1, ego16, Wgc, bgc, Wbi, bbi,
                                                        (long)k * 4096, (long)k * 64,
                                                        norms[k], NTOT, FLAG);
    }

    // ---- output gather ----
    k_gather<<<12288, 64, 0, stream>>>(users, pos, neg, ue, ie, NM1, NM2, NM3, UH, IH,
                                       d_out, FLAG);
}

// Round 12
// 1218.759 us; speedup vs baseline: 4.5168x; 1.0599x over previous
//
#include <hip/hip_runtime.h>
#include <hip/hip_bf16.h>

#define N_USER 60000
#define N_ITEM 120000
#define NTOT   180000
#define NNZ_ADJ 3600000
#define NNZ_UG   960000
#define NNZ_IG  1920000

#define RSB     2048        // rows per super-bin
#define NSB_ADJ ((NTOT  + RSB - 1) / RSB)   // 88
#define NSB_UG  ((N_USER+ RSB - 1) / RSB)   // 30
#define NSB_IG  ((N_ITEM+ RSB - 1) / RSB)   // 59
#define CAPA_SB 43008       // mean 40960 + 10 sigma
#define CAPU_SB 34816
#define CAPI_SB 34816
#define CHUNK   4096

typedef __hip_bfloat16 bf16;

// load float element i from input tensor of unknown dtype: flag=1 -> fp32, 0 -> bf16
__device__ __forceinline__ float ldf(const void* p, long i, int f) {
    return f ? ((const float*)p)[i] : __bfloat162float(((const bf16*)p)[i]);
}

// pack two fp32 -> one uint holding 2 bf16
__device__ __forceinline__ unsigned pk2(float a, float b) {
    unsigned short lo = __bfloat16_as_ushort(__float2bfloat16(a));
    unsigned short hi = __bfloat16_as_ushort(__float2bfloat16(b));
    return (unsigned)lo | ((unsigned)hi << 16);
}

// extract bf16 element kk (0..7, compile-time under unroll) of a uint4 as fp32
__device__ __forceinline__ float bfx(uint4 q, int kk) {
    unsigned u = ((kk >> 1) == 0) ? q.x : ((kk >> 1) == 1) ? q.y : ((kk >> 1) == 2) ? q.z : q.w;
    return __uint_as_float((kk & 1) ? (u & 0xFFFF0000u) : (u << 16));
}

// ---------------- dtype detector (adj_vals >= 0 -> bf16 words have bit15==0) ----
__global__ void k_detect(const void* __restrict__ vals, int* __restrict__ flag) {
    if (threadIdx.x == 0 && blockIdx.x == 0) {
        const unsigned short* w = (const unsigned short*)vals;
        int cnt = 0;
        for (int i = 0; i < 512; i += 2) cnt += (w[i] >> 15) & 1;
        *flag = (cnt > 16) ? 1 : 0;
    }
}

// ---------------- cast user/item emb -> ego bf16 ----------------
__global__ __launch_bounds__(256) void k_cast16(const void* __restrict__ ue,
                                                const void* __restrict__ ie,
                                                bf16* __restrict__ ego16,
                                                const int* __restrict__ flag) {
    int f = *flag;
    long i = (long)blockIdx.x * 256 + threadIdx.x;   // NTOT*64 = 11,520,000
    const long uN = (long)N_USER * 64;
    if (i < (long)NTOT * 64) {
        float v = (i < uN) ? ldf(ue, i, f) : ldf(ie, i - uN, f);
        ego16[i] = __float2bfloat16(v);
    }
}

// ================= two-level binned build =================
__global__ __launch_bounds__(256) void k_initpos(int* __restrict__ sbpos, int nsb, int cap) {
    int i = blockIdx.x * 256 + threadIdx.x;
    if (i < nsb) sbpos[i * 16] = i * cap;
}

// L1: partition edges into <=88 super-bins (2048 rows each).
// Record: {rl(11b)<<18 | col(18b), val_f32}
__global__ __launch_bounds__(256) void k_part(const int* __restrict__ rows,
                                              const int* __restrict__ cols,
                                              const void* __restrict__ vals,
                                              uint2* __restrict__ rec,
                                              int* __restrict__ sbpos,
                                              int nnz,
                                              const int* __restrict__ flag) {
    __shared__ int lcnt[96];
    __shared__ int lbase[96];
    int f = *flag;
    int t = threadIdx.x;
    int base = blockIdx.x * CHUNK;
    if (t < 96) lcnt[t] = 0;
    __syncthreads();
    for (int k = 0; k < CHUNK / 256; k++) {
        int e = base + k * 256 + t;
        if (e < nnz) atomicAdd(&lcnt[rows[e] >> 11], 1);
    }
    __syncthreads();
    if (t < 96) {
        int c = lcnt[t];
        lbase[t] = c ? atomicAdd(&sbpos[t * 16], c) : 0;
        lcnt[t] = 0;
    }
    __syncthreads();
    for (int k = 0; k < CHUNK / 256; k++) {
        int e = base + k * 256 + t;
        if (e < nnz) {
            int r = rows[e];
            int sb = r >> 11;
            int o = atomicAdd(&lcnt[sb], 1);
            unsigned meta = ((unsigned)(r & 2047) << 18) | (unsigned)cols[e];
            rec[lbase[sb] + o] = make_uint2(meta, __float_as_uint(ldf(vals, e, f)));
        }
    }
}

// L2: per-super-bin counting sort into row order; emits absolute [rstart, rend).
__global__ __launch_bounds__(1024) void k_sortsb(const uint2* __restrict__ rec,
                                                 uint2* __restrict__ rec2,
                                                 int* __restrict__ rstart,
                                                 int* __restrict__ rend,
                                                 const int* __restrict__ sbpos,
                                                 int cap, int n_rows) {
    __shared__ int cnt[RSB];
    __shared__ int pos[RSB];
    __shared__ int carry;
    int b = blockIdx.x, t = threadIdx.x;
    int s = b * cap;
    int e = sbpos[b * 16];           // final fill cursor
    cnt[t] = 0; cnt[t + 1024] = 0;
    if (t == 0) carry = 0;
    __syncthreads();
    for (int j = s + t; j < e; j += 1024)
        atomicAdd(&cnt[rec[j].x >> 18], 1);
    __syncthreads();
    for (int tile = 0; tile < 2; tile++) {
        int i = tile * 1024 + t;
        int v = cnt[i];
        pos[i] = v;
        __syncthreads();
        for (int d = 1; d < 1024; d <<= 1) {
            int w = (t >= d) ? pos[i - d] : 0;
            __syncthreads();
            if (t >= d) pos[i] += w;
            __syncthreads();
        }
        int inc = pos[i];            // inclusive within tile
        int ex  = carry + inc - v;   // exclusive global
        __syncthreads();
        pos[i] = ex;
        if (t == 1023) carry += inc;
        __syncthreads();
    }
    int row0 = b * RSB;
    for (int i = t; i < RSB; i += 1024) {
        int row = row0 + i;
        if (row < n_rows) {
            rstart[row] = s + pos[i];
            rend[row]   = s + pos[i] + cnt[i];
        }
    }
    __syncthreads();
    for (int j = s + t; j < e; j += 1024) {
        uint2 r = rec[j];
        int o = atomicAdd(&pos[r.x >> 18], 1);
        rec2[s + o] = r;
    }
}

// ================= CSR SpMM, bf16 x: one row per 8-lane octet =================
// MODE 1: out = bf16 S row (stride 64)
// MODE 2: out = interleaved bf16 [S(8)|P(8)]x8 row (stride 128), P = Ein .* S
template <int MODE>
__global__ __launch_bounds__(256) void k_spmm_bf(const int* __restrict__ rstart,
                                                 const int* __restrict__ rend,
                                                 const uint2* __restrict__ rec,
                                                 const bf16* __restrict__ x,
                                                 bf16* __restrict__ out,
                                                 const bf16* __restrict__ Ein,
                                                 int n_rows) {
    int row = blockIdx.x * 32 + (threadIdx.x >> 3);
    int p = threadIdx.x & 7;
    if (row >= n_rows) return;
    int s = rstart[row], e = rend[row];
    const uint4* xb = (const uint4*)x;   // 8 bf16 per uint4
    float a[8];
#pragma unroll
    for (int i = 0; i < 8; i++) a[i] = 0.0f;
    for (int j = s; j < e; j++) {
        uint2 r = rec[j];
        int col = r.x & 0x3FFFF;
        float v = __uint_as_float(r.y);
        uint4 q = xb[(long)col * 8 + p];
        a[0] += v * __uint_as_float(q.x << 16);
        a[1] += v * __uint_as_float(q.x & 0xFFFF0000u);
        a[2] += v * __uint_as_float(q.y << 16);
        a[3] += v * __uint_as_float(q.y & 0xFFFF0000u);
        a[4] += v * __uint_as_float(q.z << 16);
        a[5] += v * __uint_as_float(q.z & 0xFFFF0000u);
        a[6] += v * __uint_as_float(q.w << 16);
        a[7] += v * __uint_as_float(q.w & 0xFFFF0000u);
    }
    if (MODE == 1) {
        *(uint4*)(out + (long)row * 64 + p * 8) =
            make_uint4(pk2(a[0], a[1]), pk2(a[2], a[3]),
                       pk2(a[4], a[5]), pk2(a[6], a[7]));
    } else {
        uint4 eq = *(const uint4*)(Ein + (long)row * 64 + p * 8);
        float pr[8];
        pr[0] = a[0] * __uint_as_float(eq.x << 16);
        pr[1] = a[1] * __uint_as_float(eq.x & 0xFFFF0000u);
        pr[2] = a[2] * __uint_as_float(eq.y << 16);
        pr[3] = a[3] * __uint_as_float(eq.y & 0xFFFF0000u);
        pr[4] = a[4] * __uint_as_float(eq.z << 16);
        pr[5] = a[5] * __uint_as_float(eq.z & 0xFFFF0000u);
        pr[6] = a[6] * __uint_as_float(eq.w << 16);
        pr[7] = a[7] * __uint_as_float(eq.w & 0xFFFF0000u);
        bf16* ob = out + (long)row * 128 + p * 16;
        *(uint4*)ob = make_uint4(pk2(a[0], a[1]), pk2(a[2], a[3]),
                                 pk2(a[4], a[5]), pk2(a[6], a[7]));
        *(uint4*)(ob + 8) = make_uint4(pk2(pr[0], pr[1]), pk2(pr[2], pr[3]),
                                       pk2(pr[4], pr[5]), pk2(pr[6], pr[7]));
    }
}

// ---------------- Y[M,64] = act(X16[M,64] @ W[64,64] + b) -> bf16 --------------
// 4 rows x 8 cols/thread; bf16 X; prefetch group g+1 while computing g
// (round-11 lesson: load-to-use distance was the wall, not bytes).
template <int ACT>
__global__ __launch_bounds__(256) void k_gemm64(const bf16* __restrict__ X,
                                                const void* __restrict__ W,
                                                const void* __restrict__ b,
                                                bf16* __restrict__ Y, int M,
                                                const int* __restrict__ flag) {
    __shared__ float Wl[64][64];
    __shared__ float bl[64];
    int f = *flag;
    int tid = threadIdx.x;
    for (int i = tid; i < 4096; i += 256) Wl[i >> 6][i & 63] = ldf(W, i, f);
    if (tid < 64) bl[tid] = ldf(b, tid, f);
    __syncthreads();

    int lane = tid & 63;
    int wv = tid >> 6;
    int cg = lane & 7;
    int ro = lane >> 3;
    int jh = cg * 8;
    int rbase = blockIdx.x * 128 + wv * 32 + ro;

    bool rv[4];
    long ra[4];
#pragma unroll
    for (int i = 0; i < 4; i++) {
        int r = rbase + 8 * i;
        rv[i] = r < M;
        ra[i] = (long)(rv[i] ? r : M - 1) * 64;
    }

    float acc[4][8];
#pragma unroll
    for (int i = 0; i < 4; i++)
#pragma unroll
        for (int j = 0; j < 8; j++) acc[i][j] = bl[jh + j];

    uint4 xc[4], xn[4];
#pragma unroll
    for (int i = 0; i < 4; i++) xc[i] = *(const uint4*)(X + ra[i]);

    for (int g = 0; g < 8; g++) {
        if (g < 7) {
#pragma unroll
            for (int i = 0; i < 4; i++) xn[i] = *(const uint4*)(X + ra[i] + (g + 1) * 8);
        }
#pragma unroll
        for (int kk = 0; kk < 8; kk++) {
            float4 wa = *(const float4*)&Wl[g * 8 + kk][jh];
            float4 wb = *(const float4*)&Wl[g * 8 + kk][jh + 4];
#pragma unroll
            for (int i = 0; i < 4; i++) {
                float xs = bfx(xc[i], kk);
                acc[i][0] += xs * wa.x;
                acc[i][1] += xs * wa.y;
                acc[i][2] += xs * wa.z;
                acc[i][3] += xs * wa.w;
                acc[i][4] += xs * wb.x;
                acc[i][5] += xs * wb.y;
                acc[i][6] += xs * wb.z;
                acc[i][7] += xs * wb.w;
            }
        }
#pragma unroll
        for (int i = 0; i < 4; i++) xc[i] = xn[i];
    }

#pragma unroll
    for (int i = 0; i < 4; i++) {
#pragma unroll
        for (int j = 0; j < 8; j++) {
            float v = acc[i][j];
            if (ACT == 2) v = fmaxf(v, 0.0f);
            else          v = (v > 0.0f) ? v : (expf(v) - 1.0f);
            acc[i][j] = v;
        }
        if (rv[i]) {
            *(uint4*)(Y + ra[i] + jh) =
                make_uint4(pk2(acc[i][0], acc[i][1]), pk2(acc[i][2], acc[i][3]),
                           pk2(acc[i][4], acc[i][5]), pk2(acc[i][6], acc[i][7]));
        }
    }
}

// ---------------- fused NGCF layer + l2norm; ego bf16 updated IN PLACE --------
// Pure K=128 bf16 GEMM on interleaved SP rows ([S8|P8]x8); P precomputed in
// spmm epilogue. Prefetch next k8-group; norm via shfl_xor 1/2/4.
__global__ __launch_bounds__(256) void k_layer(const bf16* __restrict__ SP,
                                               bf16* __restrict__ E16,
                                               const void* __restrict__ Wgc,
                                               const void* __restrict__ bgc,
                                               const void* __restrict__ Wbi,
                                               const void* __restrict__ bbi,
                                               long woff, long boff,
                                               bf16* __restrict__ nm, int M,
                                               const int* __restrict__ flag) {
    __shared__ float W1[64][64];
    __shared__ float W2[64][64];
    __shared__ float bl[64];
    int f = *flag;
    int tid = threadIdx.x;
    for (int i = tid; i < 4096; i += 256) {
        W1[i >> 6][i & 63] = ldf(Wgc, woff + i, f);
        W2[i >> 6][i & 63] = ldf(Wbi, woff + i, f);
    }
    if (tid < 64) bl[tid] = ldf(bgc, boff + tid, f) + ldf(bbi, boff + tid, f);
    __syncthreads();

    int lane = tid & 63;
    int wv = tid >> 6;
    int cg = lane & 7;
    int ro = lane >> 3;
    int jh = cg * 8;
    int rbase = blockIdx.x * 128 + wv * 32 + ro;

    bool rv[4];
    long ra[4];   // SP row base (stride 128)
    long re[4];   // E16/nm row base (stride 64)
#pragma unroll
    for (int i = 0; i < 4; i++) {
        int r = rbase + 8 * i;
        rv[i] = r < M;
        long rr = (long)(rv[i] ? r : M - 1);
        ra[i] = rr * 128;
        re[i] = rr * 64;
    }

    float acc[4][8];
#pragma unroll
    for (int i = 0; i < 4; i++)
#pragma unroll
        for (int j = 0; j < 8; j++) acc[i][j] = bl[jh + j];

    uint4 sc[4], pc[4], sn[4], pn[4];
#pragma unroll
    for (int i = 0; i < 4; i++) {
        sc[i] = *(const uint4*)(SP + ra[i]);
        pc[i] = *(const uint4*)(SP + ra[i] + 8);
    }

    for (int g = 0; g < 8; g++) {
        if (g < 7) {
#pragma unroll
            for (int i = 0; i < 4; i++) {
                sn[i] = *(const uint4*)(SP + ra[i] + (g + 1) * 16);
                pn[i] = *(const uint4*)(SP + ra[i] + (g + 1) * 16 + 8);
            }
        }
#pragma unroll
        for (int kk = 0; kk < 8; kk++) {
            float4 w1a = *(const float4*)&W1[g * 8 + kk][jh];
            float4 w1b = *(const float4*)&W1[g * 8 + kk][jh + 4];
            float4 w2a = *(const float4*)&W2[g * 8 + kk][jh];
            float4 w2b = *(const float4*)&W2[g * 8 + kk][jh + 4];
#pragma unroll
            for (int i = 0; i < 4; i++) {
                float xs = bfx(sc[i], kk);
                float xp = bfx(pc[i], kk);
                acc[i][0] += xs * w1a.x + xp * w2a.x;
                acc[i][1] += xs * w1a.y + xp * w2a.y;
                acc[i][2] += xs * w1a.z + xp * w2a.z;
                acc[i][3] += xs * w1a.w + xp * w2a.w;
                acc[i][4] += xs * w1b.x + xp * w2b.x;
                acc[i][5] += xs * w1b.y + xp * w2b.y;
                acc[i][6] += xs * w1b.z + xp * w2b.z;
                acc[i][7] += xs * w1b.w + xp * w2b.w;
            }
        }
#pragma unroll
        for (int i = 0; i < 4; i++) { sc[i] = sn[i]; pc[i] = pn[i]; }
    }

#pragma unroll
    for (int i = 0; i < 4; i++) {
        float ss = 0.0f;
#pragma unroll
        for (int j = 0; j < 8; j++) {
            float v = acc[i][j];
            v = (v > 0.0f) ? v : 0.2f * v;
            acc[i][j] = v;
            ss += v * v;
        }
        ss += __shfl_xor(ss, 1, 64);   // reduce across the 8 column groups
        ss += __shfl_xor(ss, 2, 64);
        ss += __shfl_xor(ss, 4, 64);
        float sc2 = 1.0f / fmaxf(sqrtf(ss), 1e-12f);
        if (rv[i]) {
            *(uint4*)(E16 + re[i] + jh) =
                make_uint4(pk2(acc[i][0], acc[i][1]), pk2(acc[i][2], acc[i][3]),
                           pk2(acc[i][4], acc[i][5]), pk2(acc[i][6], acc[i][7]));
            *(uint4*)(nm + re[i] + jh) =
                make_uint4(pk2(acc[i][0] * sc2, acc[i][1] * sc2),
                           pk2(acc[i][2] * sc2, acc[i][3] * sc2),
                           pk2(acc[i][4] * sc2, acc[i][5] * sc2),
                           pk2(acc[i][6] * sc2, acc[i][7] * sc2));
        }
    }
}

// ---------------- final gather into output ----------------
__global__ __launch_bounds__(64) void k_gather(const int* __restrict__ users,
                                               const int* __restrict__ pos,
                                               const int* __restrict__ neg,
                                               const void* __restrict__ ue,
                                               const void* __restrict__ ie,
                                               const bf16* __restrict__ n1,
                                               const bf16* __restrict__ n2,
                                               const bf16* __restrict__ n3,
                                               const bf16* __restrict__ uh,
                                               const bf16* __restrict__ ih,
                                               void* __restrict__ out,
                                               const int* __restrict__ flag) {
    int f = *flag;
    int b = blockIdx.x;           // 0..12287: [users | pos | neg] x 4096
    int which = b >> 12;
    int s = b & 4095;
    int lane = threadIdx.x;       // 64
    long ebase, nbase;
    const void* e0;
    const bf16* hh;
    if (which == 0) {
        int r = users[s];
        e0 = ue; ebase = (long)r * 64;
        hh = uh + (long)r * 64;
        nbase = (long)r * 64;
    } else {
        int r = (which == 1) ? pos[s] : neg[s];
        e0 = ie; ebase = (long)r * 64;
        hh = ih + (long)r * 64;
        nbase = (long)(N_USER + r) * 64;
    }
    float o0 = ldf(e0, ebase + lane, f);
    float o1 = __bfloat162float(n1[nbase + lane]);
    float o2 = __bfloat162float(n2[nbase + lane]);
    float o3 = __bfloat162float(n3[nbase + lane]);
    float o4 = __bfloat162float(hh[lane]);
    long ob = (long)b * 320;
    if (f) {
        float* o = (float*)out + ob;
        o[lane] = o0; o[64 + lane] = o1; o[128 + lane] = o2;
        o[192 + lane] = o3; o[256 + lane] = o4;
    } else {
        bf16* o = (bf16*)out + ob;
        o[lane]       = __float2bfloat16(o0);
        o[64 + lane]  = __float2bfloat16(o1);
        o[128 + lane] = __float2bfloat16(o2);
        o[192 + lane] = __float2bfloat16(o3);
        o[256 + lane] = __float2bfloat16(o4);
    }
}

// host-side helper: two-level build of row-sorted packed records for one graph
static void build_graph(const int* rows, const int* cols, const void* vals,
                        int nnz, int nsb, int cap, int n_rows,
                        int* sbpos, uint2* recTmp, uint2* rec2,
                        int* rstart, int* rend,
                        const int* FLAG, hipStream_t stream) {
    k_initpos<<<1, 256, 0, stream>>>(sbpos, nsb, cap);
    k_part<<<(nnz + CHUNK - 1) / CHUNK, 256, 0, stream>>>(rows, cols, vals, recTmp, sbpos, nnz, FLAG);
    k_sortsb<<<nsb, 1024, 0, stream>>>(recTmp, rec2, rstart, rend, sbpos, cap, n_rows);
}

extern "C" void kernel_launch(void* const* d_in, const int* in_sizes, int n_in,
                              void* d_out, int out_size, void* d_ws, size_t ws_size,
                              hipStream_t stream) {
    const int* users = (const int*)d_in[0];
    const int* pos   = (const int*)d_in[1];
    const int* neg   = (const int*)d_in[2];
    const int* adj_r = (const int*)d_in[3];
    const int* adj_c = (const int*)d_in[4];
    const void* adj_v = d_in[5];
    const int* ug_r  = (const int*)d_in[6];
    const int* ug_c  = (const int*)d_in[7];
    const void* ug_v = d_in[8];
    const int* ig_r  = (const int*)d_in[9];
    const int* ig_c  = (const int*)d_in[10];
    const void* ig_v = d_in[11];
    const void* ue   = d_in[12];
    const void* ie   = d_in[13];
    const void* Wgc  = d_in[14];
    const void* bgc  = d_in[15];
    const void* Wbi  = d_in[16];
    const void* bbi  = d_in[17];
    const void* Wu0  = d_in[18];
    const void* bu0  = d_in[19];
    const void* Wu1  = d_in[20];
    const void* bu1  = d_in[21];
    const void* Wi0  = d_in[22];
    const void* bi0  = d_in[23];
    const void* Wi1  = d_in[24];
    const void* bi1  = d_in[25];

    char* ws = (char*)d_ws;
    int*   FLAG  = (int*)(ws + 0);                       // 256 B
    bf16*  SP16A = (bf16*)(ws + 256);                    // NTOT*128*2 = 46,080,000
    bf16*  S16T  = (bf16*)(ws + 46080256L);              // N_ITEM*64*2 = 15,360,000
    bf16*  ego16 = (bf16*)(ws + 61440256L);              // 23,040,000
    bf16*  UH    = (bf16*)(ws + 84480256L);              //  7,680,000
    bf16*  IH    = (bf16*)(ws + 92160256L);              // 15,360,000
    bf16*  NM1   = (bf16*)(ws + 107520256L);             // 23,040,000
    bf16*  NM2   = (bf16*)(ws + 130560256L);             // 23,040,000
    bf16*  NM3   = (bf16*)(ws + 153600256L);             // 23,040,000
    // T2 (bf16, <=15.36 MB) aliases NM2: dead before layer k=1 writes NM2
    bf16*  T2    = (bf16*)(ws + 130560256L);
    // recTmp aliases SP16A: builds finish before first adj spmm writes SP16A
    uint2* recTmp = (uint2*)(ws + 256);
    uint2* rec2A = (uint2*)(ws + 176640256L);            // 30,277,632
    uint2* rec2U = (uint2*)(ws + 206917888L);            //  8,355,840
    uint2* rec2I = (uint2*)(ws + 215273728L);            // 16,433,152
    int* rstartA = (int*)(ws + 231706880L);              //    720,000
    int* rendA   = (int*)(ws + 232426880L);              //    720,000
    int* rstartU = (int*)(ws + 233146880L);              //    240,000
    int* rendU   = (int*)(ws + 233386880L);              //    240,000
    int* rstartI = (int*)(ws + 233626880L);              //    480,000
    int* rendI   = (int*)(ws + 234106880L);              //    480,000
    int* sbpos   = (int*)(ws + 234586880L);              //      6,144
                                                         // end 234,593,024 (< 261,120,256 proven)

    k_detect<<<1, 64, 0, stream>>>(adj_v, FLAG);
    k_cast16<<<45000, 256, 0, stream>>>(ue, ie, ego16, FLAG);

    // ---- two-level build of row-sorted packed records (recTmp aliases SP16A) ----
    build_graph(ug_r,  ug_c,  ug_v,  NNZ_UG,  NSB_UG,  CAPU_SB, N_USER,
                sbpos, recTmp, rec2U, rstartU, rendU, FLAG, stream);
    build_graph(ig_r,  ig_c,  ig_v,  NNZ_IG,  NSB_IG,  CAPI_SB, N_ITEM,
                sbpos, recTmp, rec2I, rstartI, rendI, FLAG, stream);
    build_graph(adj_r, adj_c, adj_v, NNZ_ADJ, NSB_ADJ, CAPA_SB, NTOT,
                sbpos, recTmp, rec2A, rstartA, rendA, FLAG, stream);

    // ---- user MLP branch (bf16 S throughout) ----
    k_spmm_bf<1><<<(N_USER + 31) / 32, 256, 0, stream>>>(rstartU, rendU, rec2U, ego16, S16T, nullptr, N_USER);
    k_gemm64<1><<<(N_USER + 127) / 128, 256, 0, stream>>>(S16T, Wu0, bu0, T2, N_USER, FLAG);
    k_spmm_bf<1><<<(N_USER + 31) / 32, 256, 0, stream>>>(rstartU, rendU, rec2U, T2, S16T, nullptr, N_USER);
    k_gemm64<2><<<(N_USER + 127) / 128, 256, 0, stream>>>(S16T, Wu1, bu1, UH, N_USER, FLAG);

    // ---- item MLP branch ----
    const bf16* ego16I = ego16 + (size_t)N_USER * 64;
    k_spmm_bf<1><<<(N_ITEM + 31) / 32, 256, 0, stream>>>(rstartI, rendI, rec2I, ego16I, S16T, nullptr, N_ITEM);
    k_gemm64<1><<<(N_ITEM + 127) / 128, 256, 0, stream>>>(S16T, Wi0, bi0, T2, N_ITEM, FLAG);
    k_spmm_bf<1><<<(N_ITEM + 31) / 32, 256, 0, stream>>>(rstartI, rendI, rec2I, T2, S16T, nullptr, N_ITEM);
    k_gemm64<2><<<(N_ITEM + 127) / 128, 256, 0, stream>>>(S16T, Wi1, bi1, IH, N_ITEM, FLAG);

    // ---- 3 NGCF layers: spmm emits interleaved [S|P] bf16; layer = K=128 GEMM ----
    bf16* norms[3] = {NM1, NM2, NM3};
    for (int k = 0; k < 3; k++) {
        k_spmm_bf<2><<<(NTOT + 31) / 32, 256, 0, stream>>>(rstartA, rendA, rec2A, ego16, SP16A, ego16, NTOT);
        k_layer<<<(NTOT + 127) / 128, 256, 0, stream>>>(SP16A, ego16, Wgc, bgc, Wbi, bbi,
                                                        (long)k * 4096, (long)k * 64,
                                                        norms[k], NTOT, FLAG);
    }

    // ---- output gather ----
    k_gather<<<12288, 64, 0, stream>>>(users, pos, neg, ue, ie, NM1, NM2, NM3, UH, IH,
                                       d_out, FLAG);
}